// Round 2
// baseline (857.359 us; speedup 1.0000x reference)
//
#include <hip/hip_runtime.h>

#define EPS_BN 1e-5f

// ---------------------------------------------------------------------------
// Problem constants: x[4,256,256,64] f32, mask[4,256,256] i32 (active==0),
// w1[3,3,64,128], w2[3,3,128,128], out[4,128,128,128] f32.
// ---------------------------------------------------------------------------

__global__ __launch_bounds__(256) void mask_kernel(const int* __restrict__ mask,
                                                   unsigned char* __restrict__ m1,
                                                   int* __restrict__ cnt)
{
    int idx = blockIdx.x * 256 + threadIdx.x;   // 4*128*128 = 65536
    int ow = idx & 127;
    int oh = (idx >> 7) & 127;
    int b  = idx >> 14;
    bool act = false;
    #pragma unroll
    for (int kh = 0; kh < 3; ++kh) {
        int ih = 2*oh - 1 + kh;
        if ((unsigned)ih >= 256u) continue;
        #pragma unroll
        for (int kw = 0; kw < 3; ++kw) {
            int iw = 2*ow - 1 + kw;
            if ((unsigned)iw >= 256u) continue;
            if (mask[(b*256 + ih)*256 + iw] == 0) act = true;
        }
    }
    m1[idx] = act ? 1 : 0;
    unsigned long long bal = __ballot(act);
    if ((threadIdx.x & 63) == 0)
        atomicAdd(cnt, (int)__popcll(bal));
}

// conv1: 3x3 stride2 pad1, Cin=64 -> Cout=128, input masked by (mask==0).
// Block = one (b,oh) x 16 ow. Threads: co_idx = t&31 (4 co), ow_idx = t>>5 (2 ow).
__global__ __launch_bounds__(256) void conv1_kernel(const float* __restrict__ x,
                                                    const int* __restrict__ mask,
                                                    const float* __restrict__ w1,
                                                    const unsigned char* __restrict__ m1,
                                                    float* __restrict__ out1,
                                                    float* __restrict__ stats)
{
    __shared__ float xt[3][34][64];
    __shared__ float red[8][128];

    const int t = threadIdx.x;
    const int blk = blockIdx.x;          // 4096 = b*1024 + oh*8 + owt
    const int owt = blk & 7;
    const int oh  = (blk >> 3) & 127;
    const int b   = blk >> 10;
    const int ow0 = owt * 16;
    const int iw0 = 2*ow0 - 1;

    const int co_idx = t & 31;
    const int ow_idx = t >> 5;
    const int co = co_idx * 4;

    // stage masked input: rows 2*oh-1 .. 2*oh+1, cols iw0 .. iw0+32 (33 x 64)
    for (int r = 0; r < 3; ++r) {
        int ih = 2*oh - 1 + r;
        bool rowok = ((unsigned)ih < 256u);
        const float* rowp = x + (size_t)(b*256 + ih) * 256 * 64;
        const int*   mrow = mask + (size_t)(b*256 + ih) * 256;
        for (int idx = t; idx < 528; idx += 256) {   // 33*64/4 float4s
            int fo  = idx << 2;
            int col = fo >> 6;
            int ci4 = fo & 63;
            int iw  = iw0 + col;
            float4 v = make_float4(0.f, 0.f, 0.f, 0.f);
            if (rowok && (unsigned)iw < 256u && mrow[iw] == 0)   // active input site
                v = *(const float4*)(rowp + iw*64 + ci4);
            *(float4*)(&xt[r][col][ci4]) = v;
        }
    }
    __syncthreads();

    float4 acc0 = make_float4(0,0,0,0);
    float4 acc1 = make_float4(0,0,0,0);
    const int cc0 = 4 * ow_idx;    // local col of j=0, kw=0

    for (int kh = 0; kh < 3; ++kh) {
        for (int kw = 0; kw < 3; ++kw) {
            const float* wp = w1 + (size_t)((kh*3 + kw)*64) * 128 + co;
            const float* xp = &xt[kh][cc0 + kw][0];
            #pragma unroll 8
            for (int ci = 0; ci < 64; ++ci) {
                float4 wv = *(const float4*)(wp + ci*128);
                float xa = xp[ci];          // j=0
                float xb = xp[ci + 128];    // j=1: +2 cols * 64
                acc0.x = fmaf(xa, wv.x, acc0.x);
                acc0.y = fmaf(xa, wv.y, acc0.y);
                acc0.z = fmaf(xa, wv.z, acc0.z);
                acc0.w = fmaf(xa, wv.w, acc0.w);
                acc1.x = fmaf(xb, wv.x, acc1.x);
                acc1.y = fmaf(xb, wv.y, acc1.y);
                acc1.z = fmaf(xb, wv.z, acc1.z);
                acc1.w = fmaf(xb, wv.w, acc1.w);
            }
        }
    }

    const int owA = ow0 + 2*ow_idx;
    const size_t pbase = (size_t)(b*128 + oh) * 128;
    const float actA = m1[pbase + owA] ? 1.f : 0.f;
    const float actB = m1[pbase + owA + 1] ? 1.f : 0.f;
    *(float4*)(out1 + (pbase + owA    )*128 + co) = acc0;
    *(float4*)(out1 + (pbase + owA + 1)*128 + co) = acc1;

    // BN1 stats over active sites: per-block LDS reduce, then 256 atomics
    red[ow_idx][co+0] = actA*acc0.x + actB*acc1.x;
    red[ow_idx][co+1] = actA*acc0.y + actB*acc1.y;
    red[ow_idx][co+2] = actA*acc0.z + actB*acc1.z;
    red[ow_idx][co+3] = actA*acc0.w + actB*acc1.w;
    __syncthreads();
    if (t < 128) {
        float v = 0.f;
        #pragma unroll
        for (int r = 0; r < 8; ++r) v += red[r][t];
        atomicAdd(&stats[t], v);
    }
    __syncthreads();
    red[ow_idx][co+0] = actA*acc0.x*acc0.x + actB*acc1.x*acc1.x;
    red[ow_idx][co+1] = actA*acc0.y*acc0.y + actB*acc1.y*acc1.y;
    red[ow_idx][co+2] = actA*acc0.z*acc0.z + actB*acc1.z*acc1.z;
    red[ow_idx][co+3] = actA*acc0.w*acc0.w + actB*acc1.w*acc1.w;
    __syncthreads();
    if (t < 128) {
        float v = 0.f;
        #pragma unroll
        for (int r = 0; r < 8; ++r) v += red[r][t];
        atomicAdd(&stats[128 + t], v);
    }
}

__global__ void finalize_kernel(const float* __restrict__ stats,
                                const float* __restrict__ gamma,
                                const float* __restrict__ beta,
                                float* __restrict__ sbout,
                                const int* __restrict__ cnt)
{
    int c = threadIdx.x;   // 128
    float n = (float)(*cnt);
    float mean = stats[c] / n;
    float var  = stats[128 + c] / n - mean*mean;
    var = fmaxf(var, 0.f);
    float scale = gamma[c] * rsqrtf(var + EPS_BN);
    sbout[c]       = scale;
    sbout[128 + c] = beta[c] - mean*scale;
}

// conv2: 3x3 stride1 pad1, 128->128 on the [4,128,128,128] grid.
// BN1 + ReLU + m1 applied while filling LDS.
__global__ __launch_bounds__(256) void conv2_kernel(const float* __restrict__ out1,
                                                    const float* __restrict__ w2,
                                                    const unsigned char* __restrict__ m1,
                                                    const float* __restrict__ sb,
                                                    float* __restrict__ outraw,
                                                    float* __restrict__ stats)
{
    __shared__ float yt[3][18][128];
    __shared__ float red[8][128];
    __shared__ float sc[128], bi[128];

    const int t = threadIdx.x;
    const int blk = blockIdx.x;
    const int owt = blk & 7;
    const int oh  = (blk >> 3) & 127;
    const int b   = blk >> 10;
    const int ow0 = owt * 16;

    if (t < 128) { sc[t] = sb[t]; bi[t] = sb[128 + t]; }
    __syncthreads();

    const int co_idx = t & 31;
    const int ow_idx = t >> 5;
    const int co = co_idx * 4;

    for (int r = 0; r < 3; ++r) {
        int ih = oh - 1 + r;
        bool rowok = ((unsigned)ih < 128u);
        const float* rowp = out1 + (size_t)(b*128 + ih) * 128 * 128;
        const unsigned char* mrow = m1 + (size_t)(b*128 + ih) * 128;
        for (int idx = t; idx < 576; idx += 256) {   // 18*128/4
            int fo  = idx << 2;
            int col = fo >> 7;
            int c4  = fo & 127;
            int ow  = ow0 - 1 + col;
            float4 v = make_float4(0.f, 0.f, 0.f, 0.f);
            if (rowok && (unsigned)ow < 128u && mrow[ow]) {
                float4 rv = *(const float4*)(rowp + ow*128 + c4);
                v.x = fmaxf(fmaf(rv.x, sc[c4+0], bi[c4+0]), 0.f);
                v.y = fmaxf(fmaf(rv.y, sc[c4+1], bi[c4+1]), 0.f);
                v.z = fmaxf(fmaf(rv.z, sc[c4+2], bi[c4+2]), 0.f);
                v.w = fmaxf(fmaf(rv.w, sc[c4+3], bi[c4+3]), 0.f);
            }
            *(float4*)(&yt[r][col][c4]) = v;
        }
    }
    __syncthreads();

    float4 acc0 = make_float4(0,0,0,0);
    float4 acc1 = make_float4(0,0,0,0);
    const int cc0 = 2 * ow_idx;

    for (int kh = 0; kh < 3; ++kh) {
        for (int kw = 0; kw < 3; ++kw) {
            const float* wp = w2 + (size_t)((kh*3 + kw)*128) * 128 + co;
            const float* xp = &yt[kh][cc0 + kw][0];
            #pragma unroll 8
            for (int ci = 0; ci < 128; ++ci) {
                float4 wv = *(const float4*)(wp + ci*128);
                float xa = xp[ci];          // j=0
                float xb = xp[ci + 128];    // j=1: +1 col * 128
                acc0.x = fmaf(xa, wv.x, acc0.x);
                acc0.y = fmaf(xa, wv.y, acc0.y);
                acc0.z = fmaf(xa, wv.z, acc0.z);
                acc0.w = fmaf(xa, wv.w, acc0.w);
                acc1.x = fmaf(xb, wv.x, acc1.x);
                acc1.y = fmaf(xb, wv.y, acc1.y);
                acc1.z = fmaf(xb, wv.z, acc1.z);
                acc1.w = fmaf(xb, wv.w, acc1.w);
            }
        }
    }

    const int owA = ow0 + 2*ow_idx;
    const size_t pbase = (size_t)(b*128 + oh) * 128;
    const float actA = m1[pbase + owA] ? 1.f : 0.f;
    const float actB = m1[pbase + owA + 1] ? 1.f : 0.f;
    *(float4*)(outraw + (pbase + owA    )*128 + co) = acc0;
    *(float4*)(outraw + (pbase + owA + 1)*128 + co) = acc1;

    red[ow_idx][co+0] = actA*acc0.x + actB*acc1.x;
    red[ow_idx][co+1] = actA*acc0.y + actB*acc1.y;
    red[ow_idx][co+2] = actA*acc0.z + actB*acc1.z;
    red[ow_idx][co+3] = actA*acc0.w + actB*acc1.w;
    __syncthreads();
    if (t < 128) {
        float v = 0.f;
        #pragma unroll
        for (int r = 0; r < 8; ++r) v += red[r][t];
        atomicAdd(&stats[t], v);
    }
    __syncthreads();
    red[ow_idx][co+0] = actA*acc0.x*acc0.x + actB*acc1.x*acc1.x;
    red[ow_idx][co+1] = actA*acc0.y*acc0.y + actB*acc1.y*acc1.y;
    red[ow_idx][co+2] = actA*acc0.z*acc0.z + actB*acc1.z*acc1.z;
    red[ow_idx][co+3] = actA*acc0.w*acc0.w + actB*acc1.w*acc1.w;
    __syncthreads();
    if (t < 128) {
        float v = 0.f;
        #pragma unroll
        for (int r = 0; r < 8; ++r) v += red[r][t];
        atomicAdd(&stats[128 + t], v);
    }
}

// in-place BN2 apply: out = m1 ? raw*scale2 + bias2 : 0
__global__ __launch_bounds__(256) void apply_kernel(float* __restrict__ out,
                                                    const unsigned char* __restrict__ m1,
                                                    const float* __restrict__ sb)
{
    int idx4 = blockIdx.x * 256 + threadIdx.x;   // 2,097,152 float4s
    int pos = idx4 >> 5;
    int c4  = (idx4 & 31) << 2;
    float4 v = ((const float4*)out)[idx4];
    float4 r = make_float4(0.f, 0.f, 0.f, 0.f);
    if (m1[pos]) {
        r.x = fmaf(v.x, sb[c4+0], sb[128+c4+0]);
        r.y = fmaf(v.y, sb[c4+1], sb[128+c4+1]);
        r.z = fmaf(v.z, sb[c4+2], sb[128+c4+2]);
        r.w = fmaf(v.w, sb[c4+3], sb[128+c4+3]);
    }
    ((float4*)out)[idx4] = r;
}

extern "C" void kernel_launch(void* const* d_in, const int* in_sizes, int n_in,
                              void* d_out, int out_size, void* d_ws, size_t ws_size,
                              hipStream_t stream)
{
    const float* x      = (const float*)d_in[0];
    const int*   mask   = (const int*)d_in[1];
    const float* w1     = (const float*)d_in[2];
    const float* gamma1 = (const float*)d_in[3];
    const float* beta1  = (const float*)d_in[4];
    const float* w2     = (const float*)d_in[5];
    const float* gamma2 = (const float*)d_in[6];
    const float* beta2  = (const float*)d_in[7];
    float* out = (float*)d_out;

    // workspace layout
    float* out1  = (float*)d_ws;                 // 8,388,608 f32 (conv1 raw)
    float* stats = out1 + 8388608;               // 512: sum1,sq1,sum2,sq2
    float* sb    = stats + 512;                  // 512: scale1,bias1,scale2,bias2
    int*   cnt   = (int*)(sb + 512);             // 4 ints
    unsigned char* m1 = (unsigned char*)(cnt + 4);   // 65536 bytes

    hipMemsetAsync(stats, 0, (512 + 512 + 4) * sizeof(float), stream);

    mask_kernel<<<256, 256, 0, stream>>>(mask, m1, cnt);
    conv1_kernel<<<4096, 256, 0, stream>>>(x, mask, w1, m1, out1, stats);
    finalize_kernel<<<1, 128, 0, stream>>>(stats, gamma1, beta1, sb, cnt);
    conv2_kernel<<<4096, 256, 0, stream>>>(out1, w2, m1, sb, out, stats + 256);
    finalize_kernel<<<1, 128, 0, stream>>>(stats + 256, gamma2, beta2, sb + 256, cnt);
    apply_kernel<<<8192, 256, 0, stream>>>(out, m1, sb + 256);
}

// Round 5
// 297.815 us; speedup vs baseline: 2.8788x; 2.8788x over previous
//
#include <hip/hip_runtime.h>

#define EPS_BN 1e-5f

typedef unsigned char uchar;
typedef short short8 __attribute__((ext_vector_type(8)));
typedef float f32x4 __attribute__((ext_vector_type(4)));

__device__ __forceinline__ ushort f2bf(float f) {
    unsigned u = __float_as_uint(f);
    return (ushort)((u + 0x7FFFu + ((u >> 16) & 1u)) >> 16);   // RNE
}
__device__ __forceinline__ float bf2f(ushort h) {
    return __uint_as_float(((unsigned)h) << 16);
}

// ---------------------------------------------------------------------------
// x[4,256,256,64] f32, mask[4,256,256] i32 (active==0), w1[3,3,64,128],
// w2[3,3,128,128], out[4,128,128,128] f32.
// Pipeline: mask -> xb=bf16(x*act) (in d_out) -> conv1(MFMA)->out1 bf16 raw
//   -> stats1 -> sb1 -> bnrelu(out1 in-place) -> conv2(MFMA)->d_out f32 raw
//   -> stats2 -> sb2 -> apply(d_out in-place).
// MFMA fragment maps (mfma_f32_16x16x32_bf16):
//   A: lane(lr,lg)=lr+16*lg holds A[row=lr][k=lg*8..+8)
//   B: lane holds B[k=lg*8..+8)[col=lr]; weights stored [co][ci] so co=col
//   D: lane holds D[row=lg*4+r][col=lr], r=0..3
// ---------------------------------------------------------------------------

__global__ __launch_bounds__(256) void mask_kernel(const int* __restrict__ mask,
                                                   uchar* __restrict__ m1,
                                                   int* __restrict__ cnt)
{
    int idx = blockIdx.x * 256 + threadIdx.x;   // 65536
    int ow = idx & 127;
    int oh = (idx >> 7) & 127;
    int b  = idx >> 14;
    bool act = false;
    #pragma unroll
    for (int kh = 0; kh < 3; ++kh) {
        int ih = 2*oh - 1 + kh;
        if ((unsigned)ih >= 256u) continue;
        #pragma unroll
        for (int kw = 0; kw < 3; ++kw) {
            int iw = 2*ow - 1 + kw;
            if ((unsigned)iw >= 256u) continue;
            if (mask[(b*256 + ih)*256 + iw] == 0) act = true;
        }
    }
    m1[idx] = act ? 1 : 0;
    unsigned long long bal = __ballot(act);
    if ((threadIdx.x & 63) == 0)
        atomicAdd(cnt, (int)__popcll(bal));
}

// masked input -> bf16: xb[px*64 + ci]
__global__ __launch_bounds__(256) void xcvt_kernel(const float* __restrict__ x,
                                                   const int* __restrict__ mask,
                                                   ushort* __restrict__ xb)
{
    int idx = blockIdx.x * 256 + threadIdx.x;   // 2,097,152 chunks of 8
    int px = idx >> 3;
    int c0 = (idx & 7) * 8;
    short8 o = {0,0,0,0,0,0,0,0};
    if (mask[px] == 0) {
        const float* p = x + (size_t)px * 64 + c0;
        #pragma unroll
        for (int j = 0; j < 8; ++j) o[j] = (short)f2bf(p[j]);
    }
    *(short8*)(xb + (size_t)px * 64 + c0) = o;
}

// weights -> bf16, transposed to [kh*3+kw][co][ci]
__global__ __launch_bounds__(256) void wcvt_kernel(const float* __restrict__ w1,
                                                   const float* __restrict__ w2,
                                                   ushort* __restrict__ w1T,
                                                   ushort* __restrict__ w2T)
{
    int idx = blockIdx.x * 256 + threadIdx.x;   // 221184 total
    if (idx < 73728) {                          // 9*128*64
        int ci = idx & 63;
        int co = (idx >> 6) & 127;
        int s  = idx >> 13;
        w1T[idx] = f2bf(w1[(s*64 + ci)*128 + co]);
    } else if (idx < 221184) {
        int i  = idx - 73728;                   // 9*128*128
        int ci = i & 127;
        int co = (i >> 7) & 127;
        int s  = i >> 14;
        w2T[i] = f2bf(w2[(s*128 + ci)*128 + co]);
    }
}

// conv1: 3x3 s2, 64->128. Block: 64 pixels (one oh row) x all 128 co.
// A-tile LDS [3][130][64] bf16, XOR-swizzle byte ^= (((c>>1)&7)<<4).
__global__ __launch_bounds__(256) void conv1_mfma(const ushort* __restrict__ xb,
                                                  const ushort* __restrict__ w1T,
                                                  ushort* __restrict__ out1)
{
    __shared__ ushort at[3 * 130 * 64];        // 49,920 B
    char* lds = (char*)at;

    const int t   = threadIdx.x;
    const int blk = blockIdx.x;                 // 1024 = b*256 + oh*2 + owt
    const int owt = blk & 1;
    const int oh  = (blk >> 1) & 127;
    const int b   = blk >> 8;
    const int ow0 = owt * 64;

    // fill: rows 2oh-1..2oh+1, cols 2*ow0-1 .. +129 (130 cols), 8 chunks/col
    for (int r = 0; r < 3; ++r) {
        int ih = 2*oh - 1 + r;
        bool rok = ((unsigned)ih < 256u);
        const ushort* rowp = xb + (size_t)(b*256 + ih) * 256 * 64;
        for (int idx = t; idx < 1040; idx += 256) {
            int c  = idx >> 3;
            int ck = idx & 7;
            int iw = 2*ow0 - 1 + c;
            short8 v = {0,0,0,0,0,0,0,0};
            if (rok && (unsigned)iw < 256u)
                v = *(const short8*)(rowp + iw*64 + ck*8);
            int ad = ((r*130 + c) << 7) + (ck << 4);
            *(short8*)(lds + (ad ^ ((((unsigned)c >> 1) & 7) << 4))) = v;
        }
    }
    __syncthreads();

    const int lane = t & 63;
    const int w  = t >> 6;
    const int wm = w >> 1, wn = w & 1;          // wave tile: 32 px x 64 co
    const int lr = lane & 15;
    const int lg = lane >> 4;

    f32x4 acc[2][4];
    #pragma unroll
    for (int mi = 0; mi < 2; ++mi)
        #pragma unroll
        for (int ni = 0; ni < 4; ++ni)
            acc[mi][ni] = (f32x4){0.f, 0.f, 0.f, 0.f};

    for (int kh = 0; kh < 3; ++kh) {
        #pragma unroll
        for (int kw = 0; kw < 3; ++kw) {
            // B fragments: w1T[(kh*3+kw)][wn*64 + ni*16 + lr][ks*32 + lg*8]
            const ushort* bwk = w1T + (size_t)(kh*3 + kw) * 128 * 64
                              + (size_t)(wn*64 + lr) * 64 + lg*8;
            const int c0 = 2*(wm*32 + lr) + kw;     // tile col of mi=0 pixel
            #pragma unroll
            for (int ks = 0; ks < 2; ++ks) {
                const int cio = ks*32 + lg*8;       // ci element offset
                const int cA1 = c0 + 32;            // +16 pixels = +32 cols
                int ad0 = ((kh*130 + c0 ) << 7) + (cio << 1);
                int ad1 = ((kh*130 + cA1) << 7) + (cio << 1);
                short8 a0 = *(const short8*)(lds + (ad0 ^ ((((unsigned)c0  >> 1) & 7) << 4)));
                short8 a1 = *(const short8*)(lds + (ad1 ^ ((((unsigned)cA1 >> 1) & 7) << 4)));
                short8 b0 = *(const short8*)(bwk +  0*64 + ks*32);
                short8 b1 = *(const short8*)(bwk + 16*64 + ks*32);
                short8 b2 = *(const short8*)(bwk + 32*64 + ks*32);
                short8 b3 = *(const short8*)(bwk + 48*64 + ks*32);
                acc[0][0] = __builtin_amdgcn_mfma_f32_16x16x32_bf16(a0, b0, acc[0][0], 0, 0, 0);
                acc[0][1] = __builtin_amdgcn_mfma_f32_16x16x32_bf16(a0, b1, acc[0][1], 0, 0, 0);
                acc[0][2] = __builtin_amdgcn_mfma_f32_16x16x32_bf16(a0, b2, acc[0][2], 0, 0, 0);
                acc[0][3] = __builtin_amdgcn_mfma_f32_16x16x32_bf16(a0, b3, acc[0][3], 0, 0, 0);
                acc[1][0] = __builtin_amdgcn_mfma_f32_16x16x32_bf16(a1, b0, acc[1][0], 0, 0, 0);
                acc[1][1] = __builtin_amdgcn_mfma_f32_16x16x32_bf16(a1, b1, acc[1][1], 0, 0, 0);
                acc[1][2] = __builtin_amdgcn_mfma_f32_16x16x32_bf16(a1, b2, acc[1][2], 0, 0, 0);
                acc[1][3] = __builtin_amdgcn_mfma_f32_16x16x32_bf16(a1, b3, acc[1][3], 0, 0, 0);
            }
        }
    }

    const size_t pix0 = (size_t)(b*128 + oh) * 128 + ow0;
    #pragma unroll
    for (int mi = 0; mi < 2; ++mi) {
        #pragma unroll
        for (int ni = 0; ni < 4; ++ni) {
            int prow = wm*32 + mi*16 + lg*4;
            int co   = wn*64 + ni*16 + lr;
            #pragma unroll
            for (int r = 0; r < 4; ++r)
                out1[(pix0 + prow + r)*128 + co] = f2bf(acc[mi][ni][r]);
        }
    }
}

// stats over active pixels: stats[0..127]=sum, [128..255]=sumsq
__global__ __launch_bounds__(256) void stats_kernel(const void* __restrict__ src,
                                                    int isbf16,
                                                    const uchar* __restrict__ m1,
                                                    float* __restrict__ stats)
{
    const int t = threadIdx.x;
    const int c = t & 127;
    const int half = t >> 7;
    const int p0 = blockIdx.x * 256 + half * 128;   // 256 blocks x 256 pixels
    float s = 0.f, q = 0.f;
    for (int i = 0; i < 128; ++i) {
        int p = p0 + i;
        if (!m1[p]) continue;
        float v = isbf16 ? bf2f(((const ushort*)src)[(size_t)p*128 + c])
                         : ((const float*)src)[(size_t)p*128 + c];
        s += v;
        q += v * v;
    }
    __shared__ float red[256];
    red[t] = s;
    __syncthreads();
    if (half == 0) atomicAdd(&stats[c], red[c] + red[128 + c]);
    __syncthreads();
    red[t] = q;
    __syncthreads();
    if (half == 0) atomicAdd(&stats[128 + c], red[c] + red[128 + c]);
}

__global__ void finalize_kernel(const float* __restrict__ stats,
                                const float* __restrict__ gamma,
                                const float* __restrict__ beta,
                                float* __restrict__ sbout,
                                const int* __restrict__ cnt)
{
    int c = threadIdx.x;   // 128
    float n = (float)(*cnt);
    float mean = stats[c] / n;
    float var  = stats[128 + c] / n - mean*mean;
    var = fmaxf(var, 0.f);
    float scale = gamma[c] * rsqrtf(var + EPS_BN);
    sbout[c]       = scale;
    sbout[128 + c] = beta[c] - mean*scale;
}

// out1 <- m1 ? relu(out1*sc+bi) : 0   (bf16 in-place)
__global__ __launch_bounds__(256) void bnrelu_kernel(ushort* __restrict__ o,
                                                     const uchar* __restrict__ m1,
                                                     const float* __restrict__ sb)
{
    int idx = blockIdx.x * 256 + threadIdx.x;   // 1,048,576 chunks of 8
    int px = idx >> 4;
    int c0 = (idx & 15) * 8;
    short8 r = {0,0,0,0,0,0,0,0};
    if (m1[px]) {
        short8 v = *(const short8*)(o + (size_t)px*128 + c0);
        #pragma unroll
        for (int j = 0; j < 8; ++j) {
            float f = fmaf(bf2f((ushort)v[j]), sb[c0+j], sb[128+c0+j]);
            r[j] = (short)f2bf(fmaxf(f, 0.f));
        }
    }
    *(short8*)(o + (size_t)px*128 + c0) = r;
}

// conv2: 3x3 s1, 128->128. Block: 64 pixels x 128 co.
// A-tile LDS [3][66][128] bf16, XOR-swizzle byte ^= ((c&7)<<4).
__global__ __launch_bounds__(256) void conv2_mfma(const ushort* __restrict__ a,
                                                  const ushort* __restrict__ w2T,
                                                  float* __restrict__ outraw)
{
    __shared__ ushort at[3 * 66 * 128];        // 50,688 B
    char* lds = (char*)at;

    const int t   = threadIdx.x;
    const int blk = blockIdx.x;                 // 1024 = b*256 + oh*2 + owt
    const int owt = blk & 1;
    const int oh  = (blk >> 1) & 127;
    const int b   = blk >> 8;
    const int ow0 = owt * 64;

    for (int r = 0; r < 3; ++r) {
        int ih = oh - 1 + r;
        bool rok = ((unsigned)ih < 128u);
        const ushort* rowp = a + (size_t)(b*128 + ih) * 128 * 128;
        for (int idx = t; idx < 1056; idx += 256) {   // 66 cols x 16 chunks
            int c  = idx >> 4;
            int ck = idx & 15;
            int ow = ow0 - 1 + c;
            short8 v = {0,0,0,0,0,0,0,0};
            if (rok && (unsigned)ow < 128u)
                v = *(const short8*)(rowp + ow*128 + ck*8);
            int ad = ((r*66 + c) << 8) + (ck << 4);
            *(short8*)(lds + (ad ^ ((c & 7) << 4))) = v;
        }
    }
    __syncthreads();

    const int lane = t & 63;
    const int w  = t >> 6;
    const int wm = w >> 1, wn = w & 1;
    const int lr = lane & 15;
    const int lg = lane >> 4;

    f32x4 acc[2][4];
    #pragma unroll
    for (int mi = 0; mi < 2; ++mi)
        #pragma unroll
        for (int ni = 0; ni < 4; ++ni)
            acc[mi][ni] = (f32x4){0.f, 0.f, 0.f, 0.f};

    for (int kh = 0; kh < 3; ++kh) {
        #pragma unroll
        for (int kw = 0; kw < 3; ++kw) {
            const ushort* bwk = w2T + (size_t)(kh*3 + kw) * 128 * 128
                              + (size_t)(wn*64 + lr) * 128 + lg*8;
            const int c0 = wm*32 + lr + kw;
            #pragma unroll
            for (int ks = 0; ks < 4; ++ks) {
                const int cio = ks*32 + lg*8;
                const int cA1 = c0 + 16;
                int ad0 = ((kh*66 + c0 ) << 8) + (cio << 1);
                int ad1 = ((kh*66 + cA1) << 8) + (cio << 1);
                short8 a0 = *(const short8*)(lds + (ad0 ^ ((c0  & 7) << 4)));
                short8 a1 = *(const short8*)(lds + (ad1 ^ ((cA1 & 7) << 4)));
                short8 b0 = *(const short8*)(bwk +  0*128 + ks*32);
                short8 b1 = *(const short8*)(bwk + 16*128 + ks*32);
                short8 b2 = *(const short8*)(bwk + 32*128 + ks*32);
                short8 b3 = *(const short8*)(bwk + 48*128 + ks*32);
                acc[0][0] = __builtin_amdgcn_mfma_f32_16x16x32_bf16(a0, b0, acc[0][0], 0, 0, 0);
                acc[0][1] = __builtin_amdgcn_mfma_f32_16x16x32_bf16(a0, b1, acc[0][1], 0, 0, 0);
                acc[0][2] = __builtin_amdgcn_mfma_f32_16x16x32_bf16(a0, b2, acc[0][2], 0, 0, 0);
                acc[0][3] = __builtin_amdgcn_mfma_f32_16x16x32_bf16(a0, b3, acc[0][3], 0, 0, 0);
                acc[1][0] = __builtin_amdgcn_mfma_f32_16x16x32_bf16(a1, b0, acc[1][0], 0, 0, 0);
                acc[1][1] = __builtin_amdgcn_mfma_f32_16x16x32_bf16(a1, b1, acc[1][1], 0, 0, 0);
                acc[1][2] = __builtin_amdgcn_mfma_f32_16x16x32_bf16(a1, b2, acc[1][2], 0, 0, 0);
                acc[1][3] = __builtin_amdgcn_mfma_f32_16x16x32_bf16(a1, b3, acc[1][3], 0, 0, 0);
            }
        }
    }

    const size_t pix0 = (size_t)(b*128 + oh) * 128 + ow0;
    #pragma unroll
    for (int mi = 0; mi < 2; ++mi) {
        #pragma unroll
        for (int ni = 0; ni < 4; ++ni) {
            int prow = wm*32 + mi*16 + lg*4;
            int co   = wn*64 + ni*16 + lr;
            #pragma unroll
            for (int r = 0; r < 4; ++r)
                outraw[(pix0 + prow + r)*128 + co] = acc[mi][ni][r];
        }
    }
}

// d_out <- m1 ? raw*sc2+bi2 : 0 (f32 in-place)
__global__ __launch_bounds__(256) void apply_kernel(float* __restrict__ out,
                                                    const uchar* __restrict__ m1,
                                                    const float* __restrict__ sb)
{
    int idx4 = blockIdx.x * 256 + threadIdx.x;   // 2,097,152 float4s
    int pos = idx4 >> 5;
    int c4  = (idx4 & 31) << 2;
    float4 v = ((const float4*)out)[idx4];
    float4 r = make_float4(0.f, 0.f, 0.f, 0.f);
    if (m1[pos]) {
        r.x = fmaf(v.x, sb[c4+0], sb[128+c4+0]);
        r.y = fmaf(v.y, sb[c4+1], sb[128+c4+1]);
        r.z = fmaf(v.z, sb[c4+2], sb[128+c4+2]);
        r.w = fmaf(v.w, sb[c4+3], sb[128+c4+3]);
    }
    ((float4*)out)[idx4] = r;
}

extern "C" void kernel_launch(void* const* d_in, const int* in_sizes, int n_in,
                              void* d_out, int out_size, void* d_ws, size_t ws_size,
                              hipStream_t stream)
{
    const float* x      = (const float*)d_in[0];
    const int*   mask   = (const int*)d_in[1];
    const float* w1     = (const float*)d_in[2];
    const float* gamma1 = (const float*)d_in[3];
    const float* beta1  = (const float*)d_in[4];
    const float* w2     = (const float*)d_in[5];
    const float* gamma2 = (const float*)d_in[6];
    const float* beta2  = (const float*)d_in[7];

    // workspace (~17.3 MB)
    ushort* out1 = (ushort*)d_ws;                    // 65536*128 bf16
    ushort* w1T  = out1 + 8388608;                   // 9*128*64
    ushort* w2T  = w1T + 73728;                      // 9*128*128
    float* stats = (float*)(w2T + 147456);           // 512 (256 per BN)
    float* sb    = stats + 512;                      // 512 (256 per BN)
    int*   cnt   = (int*)(sb + 512);                 // 4
    uchar* m1    = (uchar*)(cnt + 4);                // 65536

    // xb (masked bf16 input, 33.55 MB) lives in d_out; consumed by conv1
    // before conv2 overwrites d_out with raw f32 output.
    ushort* xb = (ushort*)d_out;
    float*  out = (float*)d_out;

    hipMemsetAsync(stats, 0, (512 + 512 + 4) * sizeof(float), stream);

    mask_kernel <<<256,  256, 0, stream>>>(mask, m1, cnt);
    xcvt_kernel <<<8192, 256, 0, stream>>>(x, mask, xb);
    wcvt_kernel <<<864,  256, 0, stream>>>(w1, w2, w1T, w2T);
    conv1_mfma  <<<1024, 256, 0, stream>>>(xb, w1T, out1);
    stats_kernel<<<256,  256, 0, stream>>>(out1, 1, m1, stats);
    finalize_kernel<<<1, 128, 0, stream>>>(stats, gamma1, beta1, sb, cnt);
    bnrelu_kernel<<<4096,256, 0, stream>>>(out1, m1, sb);
    conv2_mfma  <<<1024, 256, 0, stream>>>(out1, w2T, out);
    stats_kernel<<<256,  256, 0, stream>>>(out, 0, m1, stats + 256);
    finalize_kernel<<<1, 128, 0, stream>>>(stats + 256, gamma2, beta2, sb + 256, cnt);
    apply_kernel<<<8192, 256, 0, stream>>>(out, m1, sb + 256);
}

// Round 6
// 274.752 us; speedup vs baseline: 3.1205x; 1.0839x over previous
//
#include <hip/hip_runtime.h>

#define EPS_BN 1e-5f
#define MFMA16 __builtin_amdgcn_mfma_f32_16x16x32_bf16

typedef unsigned char uchar;
typedef short short8 __attribute__((ext_vector_type(8)));
typedef float f32x4 __attribute__((ext_vector_type(4)));

__device__ __forceinline__ ushort f2bf(float f) {
    unsigned u = __float_as_uint(f);
    return (ushort)((u + 0x7FFFu + ((u >> 16) & 1u)) >> 16);   // RNE
}
__device__ __forceinline__ float bf2f(ushort h) {
    return __uint_as_float(((unsigned)h) << 16);
}

// ---------------------------------------------------------------------------
// x[4,256,256,64] f32, mask[4,256,256] i32 (active==0), w1[3,3,64,128],
// w2[3,3,128,128], out[4,128,128,128] f32.
// Pipeline: mask -> xb=bf16(x*act) (in d_out) -> conv1(MFMA)->out1 bf16 raw
//   -> stats1 -> sb1 -> conv2(MFMA, BN1+ReLU+mask fused in LDS fill)
//   -> d_out f32 raw -> stats2 -> sb2 -> apply(d_out in-place).
// MFMA fragment maps (mfma_f32_16x16x32_bf16):
//   A: lane(lr,lg)=lr+16*lg holds A[row=lr][k=lg*8..+8)
//   B: lane holds B[k=lg*8..+8)[col=lr]; weights stored [co][ci] so co=col
//   D: lane holds D[row=lg*4+r][col=lr], r=0..3
// ---------------------------------------------------------------------------

__global__ __launch_bounds__(256) void mask_kernel(const int* __restrict__ mask,
                                                   uchar* __restrict__ m1,
                                                   int* __restrict__ cnt)
{
    int idx = blockIdx.x * 256 + threadIdx.x;   // 65536
    int ow = idx & 127;
    int oh = (idx >> 7) & 127;
    int b  = idx >> 14;
    bool act = false;
    #pragma unroll
    for (int kh = 0; kh < 3; ++kh) {
        int ih = 2*oh - 1 + kh;
        if ((unsigned)ih >= 256u) continue;
        #pragma unroll
        for (int kw = 0; kw < 3; ++kw) {
            int iw = 2*ow - 1 + kw;
            if ((unsigned)iw >= 256u) continue;
            if (mask[(b*256 + ih)*256 + iw] == 0) act = true;
        }
    }
    m1[idx] = act ? 1 : 0;
    unsigned long long bal = __ballot(act);
    if ((threadIdx.x & 63) == 0)
        atomicAdd(cnt, (int)__popcll(bal));
}

// masked input -> bf16: xb[px*64 + ci]
__global__ __launch_bounds__(256) void xcvt_kernel(const float* __restrict__ x,
                                                   const int* __restrict__ mask,
                                                   ushort* __restrict__ xb)
{
    int idx = blockIdx.x * 256 + threadIdx.x;   // 2,097,152 chunks of 8
    int px = idx >> 3;
    int c0 = (idx & 7) * 8;
    short8 o = {0,0,0,0,0,0,0,0};
    if (mask[px] == 0) {
        const float* p = x + (size_t)px * 64 + c0;
        #pragma unroll
        for (int j = 0; j < 8; ++j) o[j] = (short)f2bf(p[j]);
    }
    *(short8*)(xb + (size_t)px * 64 + c0) = o;
}

// weights -> bf16, transposed to [kh*3+kw][co][ci]
__global__ __launch_bounds__(256) void wcvt_kernel(const float* __restrict__ w1,
                                                   const float* __restrict__ w2,
                                                   ushort* __restrict__ w1T,
                                                   ushort* __restrict__ w2T)
{
    int idx = blockIdx.x * 256 + threadIdx.x;   // 221184 total
    if (idx < 73728) {                          // 9*128*64
        int ci = idx & 63;
        int co = (idx >> 6) & 127;
        int s  = idx >> 13;
        w1T[idx] = f2bf(w1[(s*64 + ci)*128 + co]);
    } else if (idx < 221184) {
        int i  = idx - 73728;                   // 9*128*128
        int ci = i & 127;
        int co = (i >> 7) & 127;
        int s  = i >> 14;
        w2T[i] = f2bf(w2[(s*128 + ci)*128 + co]);
    }
}

// conv1: 3x3 s2, 64->128. Block: 64 pixels (one oh row) x all 128 co.
// A-tile LDS [3][130][64] bf16, XOR-swizzle byte ^= (((c>>1)&7)<<4).
// B prefetched per (kh,kw) step into register double-buffer.
__global__ __launch_bounds__(256) void conv1_mfma(const ushort* __restrict__ xb,
                                                  const ushort* __restrict__ w1T,
                                                  ushort* __restrict__ out1)
{
    __shared__ ushort at[3 * 130 * 64];        // 49,920 B
    char* lds = (char*)at;

    const int t   = threadIdx.x;
    const int blk = blockIdx.x;                 // 1024 = b*256 + oh*2 + owt
    const int owt = blk & 1;
    const int oh  = (blk >> 1) & 127;
    const int b   = blk >> 8;
    const int ow0 = owt * 64;

    // fill: rows 2oh-1..2oh+1, cols 2*ow0-1 .. +129 (130 cols), 8 chunks/col
    for (int r = 0; r < 3; ++r) {
        int ih = 2*oh - 1 + r;
        bool rok = ((unsigned)ih < 256u);
        const ushort* rowp = xb + (size_t)(b*256 + ih) * 256 * 64;
        for (int idx = t; idx < 1040; idx += 256) {
            int c  = idx >> 3;
            int ck = idx & 7;
            int iw = 2*ow0 - 1 + c;
            short8 v = {0,0,0,0,0,0,0,0};
            if (rok && (unsigned)iw < 256u)
                v = *(const short8*)(rowp + iw*64 + ck*8);
            int ad = ((r*130 + c) << 7) + (ck << 4);
            *(short8*)(lds + (ad ^ ((((unsigned)c >> 1) & 7) << 4))) = v;
        }
    }
    __syncthreads();

    const int lane = t & 63;
    const int w  = t >> 6;
    const int wm = w >> 1, wn = w & 1;          // wave tile: 32 px x 64 co
    const int lr = lane & 15;
    const int lg = lane >> 4;

    f32x4 acc[2][4];
    #pragma unroll
    for (int mi = 0; mi < 2; ++mi)
        #pragma unroll
        for (int ni = 0; ni < 4; ++ni)
            acc[mi][ni] = (f32x4){0.f, 0.f, 0.f, 0.f};

    // B frags: w1T[s][wn*64 + ni*16 + lr][ks*32 + lg*8]; step stride 8192
    const ushort* bbase = w1T + (size_t)(wn*64 + lr) * 64 + lg*8;
    short8 Bb[2][8];
    #pragma unroll
    for (int ni = 0; ni < 4; ++ni)
        #pragma unroll
        for (int ks = 0; ks < 2; ++ks)
            Bb[0][ni*2 + ks] = *(const short8*)(bbase + ni*1024 + ks*32);

    #pragma unroll
    for (int s = 0; s < 9; ++s) {
        const int cur = s & 1;
        if (s < 8) {
            const ushort* bn = bbase + (size_t)(s + 1) * 8192;
            #pragma unroll
            for (int ni = 0; ni < 4; ++ni)
                #pragma unroll
                for (int ks = 0; ks < 2; ++ks)
                    Bb[cur ^ 1][ni*2 + ks] = *(const short8*)(bn + ni*1024 + ks*32);
        }
        const int kh = s / 3, kw = s % 3;
        const int c0  = 2*(wm*32 + lr) + kw;    // tile col of mi=0 pixel
        const int cA1 = c0 + 32;                // +16 pixels = +32 cols
        #pragma unroll
        for (int ks = 0; ks < 2; ++ks) {
            const int cio = ks*32 + lg*8;
            int ad0 = ((kh*130 + c0 ) << 7) + (cio << 1);
            int ad1 = ((kh*130 + cA1) << 7) + (cio << 1);
            short8 a0 = *(const short8*)(lds + (ad0 ^ ((((unsigned)c0  >> 1) & 7) << 4)));
            short8 a1 = *(const short8*)(lds + (ad1 ^ ((((unsigned)cA1 >> 1) & 7) << 4)));
            acc[0][0] = MFMA16(a0, Bb[cur][0*2+ks], acc[0][0], 0, 0, 0);
            acc[0][1] = MFMA16(a0, Bb[cur][1*2+ks], acc[0][1], 0, 0, 0);
            acc[0][2] = MFMA16(a0, Bb[cur][2*2+ks], acc[0][2], 0, 0, 0);
            acc[0][3] = MFMA16(a0, Bb[cur][3*2+ks], acc[0][3], 0, 0, 0);
            acc[1][0] = MFMA16(a1, Bb[cur][0*2+ks], acc[1][0], 0, 0, 0);
            acc[1][1] = MFMA16(a1, Bb[cur][1*2+ks], acc[1][1], 0, 0, 0);
            acc[1][2] = MFMA16(a1, Bb[cur][2*2+ks], acc[1][2], 0, 0, 0);
            acc[1][3] = MFMA16(a1, Bb[cur][3*2+ks], acc[1][3], 0, 0, 0);
        }
    }

    const size_t pix0 = (size_t)(b*128 + oh) * 128 + ow0;
    #pragma unroll
    for (int mi = 0; mi < 2; ++mi) {
        #pragma unroll
        for (int ni = 0; ni < 4; ++ni) {
            int prow = wm*32 + mi*16 + lg*4;
            int co   = wn*64 + ni*16 + lr;
            #pragma unroll
            for (int r = 0; r < 4; ++r)
                out1[(pix0 + prow + r)*128 + co] = f2bf(acc[mi][ni][r]);
        }
    }
}

// stats over active pixels: stats[0..127]=sum, [128..255]=sumsq
__global__ __launch_bounds__(256) void stats_kernel(const void* __restrict__ src,
                                                    int isbf16,
                                                    const uchar* __restrict__ m1,
                                                    float* __restrict__ stats)
{
    const int t = threadIdx.x;
    const int c = t & 127;
    const int half = t >> 7;
    const int p0 = blockIdx.x * 256 + half * 128;   // 256 blocks x 256 pixels
    float s = 0.f, q = 0.f;
    for (int i = 0; i < 128; ++i) {
        int p = p0 + i;
        if (!m1[p]) continue;
        float v = isbf16 ? bf2f(((const ushort*)src)[(size_t)p*128 + c])
                         : ((const float*)src)[(size_t)p*128 + c];
        s += v;
        q += v * v;
    }
    __shared__ float red[256];
    red[t] = s;
    __syncthreads();
    if (half == 0) atomicAdd(&stats[c], red[c] + red[128 + c]);
    __syncthreads();
    red[t] = q;
    __syncthreads();
    if (half == 0) atomicAdd(&stats[128 + c], red[c] + red[128 + c]);
}

__global__ void finalize_kernel(const float* __restrict__ stats,
                                const float* __restrict__ gamma,
                                const float* __restrict__ beta,
                                float* __restrict__ sbout,
                                const int* __restrict__ cnt)
{
    int c = threadIdx.x;   // 128
    float n = (float)(*cnt);
    float mean = stats[c] / n;
    float var  = stats[128 + c] / n - mean*mean;
    var = fmaxf(var, 0.f);
    float scale = gamma[c] * rsqrtf(var + EPS_BN);
    sbout[c]       = scale;
    sbout[128 + c] = beta[c] - mean*scale;
}

// conv2: 3x3 s1, 128->128. Block: 64 pixels x 128 co.
// A-tile LDS [3][66][128] bf16, XOR-swizzle byte ^= ((c&7)<<4).
// BN1 + ReLU + m1 fused into LDS fill; B register double-buffer prefetch.
__global__ __launch_bounds__(256) void conv2_mfma(const ushort* __restrict__ a,
                                                  const ushort* __restrict__ w2T,
                                                  const uchar* __restrict__ m1,
                                                  const float* __restrict__ sb,
                                                  float* __restrict__ outraw)
{
    __shared__ ushort at[3 * 66 * 128];        // 50,688 B
    __shared__ float scs[128], bis[128];
    char* lds = (char*)at;

    const int t   = threadIdx.x;
    const int blk = blockIdx.x;                 // 1024 = b*256 + oh*2 + owt
    const int owt = blk & 1;
    const int oh  = (blk >> 1) & 127;
    const int b   = blk >> 8;
    const int ow0 = owt * 64;

    if (t < 128) { scs[t] = sb[t]; bis[t] = sb[128 + t]; }
    __syncthreads();

    for (int r = 0; r < 3; ++r) {
        int ih = oh - 1 + r;
        bool rok = ((unsigned)ih < 128u);
        const ushort* rowp = a + (size_t)(b*128 + ih) * 128 * 128;
        const uchar*  mrow = m1 + (size_t)(b*128 + ih) * 128;
        for (int idx = t; idx < 1056; idx += 256) {   // 66 cols x 16 chunks
            int c  = idx >> 4;
            int ck = idx & 15;
            int ow = ow0 - 1 + c;
            short8 v = {0,0,0,0,0,0,0,0};
            if (rok && (unsigned)ow < 128u && mrow[ow]) {
                short8 rv = *(const short8*)(rowp + ow*128 + ck*8);
                #pragma unroll
                for (int j = 0; j < 8; ++j) {
                    float f = fmaf(bf2f((ushort)rv[j]), scs[ck*8 + j], bis[ck*8 + j]);
                    v[j] = (short)f2bf(fmaxf(f, 0.f));
                }
            }
            int ad = ((r*66 + c) << 8) + (ck << 4);
            *(short8*)(lds + (ad ^ ((c & 7) << 4))) = v;
        }
    }
    __syncthreads();

    const int lane = t & 63;
    const int w  = t >> 6;
    const int wm = w >> 1, wn = w & 1;
    const int lr = lane & 15;
    const int lg = lane >> 4;

    f32x4 acc[2][4];
    #pragma unroll
    for (int mi = 0; mi < 2; ++mi)
        #pragma unroll
        for (int ni = 0; ni < 4; ++ni)
            acc[mi][ni] = (f32x4){0.f, 0.f, 0.f, 0.f};

    // B frags: w2T[s][wn*64 + ni*16 + lr][ks*32 + lg*8]; step stride 16384
    const ushort* bbase = w2T + (size_t)(wn*64 + lr) * 128 + lg*8;
    short8 Bb[2][16];
    #pragma unroll
    for (int ni = 0; ni < 4; ++ni)
        #pragma unroll
        for (int ks = 0; ks < 4; ++ks)
            Bb[0][ni*4 + ks] = *(const short8*)(bbase + ni*2048 + ks*32);

    #pragma unroll
    for (int s = 0; s < 9; ++s) {
        const int cur = s & 1;
        if (s < 8) {
            const ushort* bn = bbase + (size_t)(s + 1) * 16384;
            #pragma unroll
            for (int ni = 0; ni < 4; ++ni)
                #pragma unroll
                for (int ks = 0; ks < 4; ++ks)
                    Bb[cur ^ 1][ni*4 + ks] = *(const short8*)(bn + ni*2048 + ks*32);
        }
        const int kh = s / 3, kw = s % 3;
        const int c0  = wm*32 + lr + kw;
        const int cA1 = c0 + 16;
        #pragma unroll
        for (int ks = 0; ks < 4; ++ks) {
            const int cio = ks*32 + lg*8;
            int ad0 = ((kh*66 + c0 ) << 8) + (cio << 1);
            int ad1 = ((kh*66 + cA1) << 8) + (cio << 1);
            short8 a0 = *(const short8*)(lds + (ad0 ^ ((c0  & 7) << 4)));
            short8 a1 = *(const short8*)(lds + (ad1 ^ ((cA1 & 7) << 4)));
            acc[0][0] = MFMA16(a0, Bb[cur][0*4+ks], acc[0][0], 0, 0, 0);
            acc[0][1] = MFMA16(a0, Bb[cur][1*4+ks], acc[0][1], 0, 0, 0);
            acc[0][2] = MFMA16(a0, Bb[cur][2*4+ks], acc[0][2], 0, 0, 0);
            acc[0][3] = MFMA16(a0, Bb[cur][3*4+ks], acc[0][3], 0, 0, 0);
            acc[1][0] = MFMA16(a1, Bb[cur][0*4+ks], acc[1][0], 0, 0, 0);
            acc[1][1] = MFMA16(a1, Bb[cur][1*4+ks], acc[1][1], 0, 0, 0);
            acc[1][2] = MFMA16(a1, Bb[cur][2*4+ks], acc[1][2], 0, 0, 0);
            acc[1][3] = MFMA16(a1, Bb[cur][3*4+ks], acc[1][3], 0, 0, 0);
        }
    }

    const size_t pix0 = (size_t)(b*128 + oh) * 128 + ow0;
    #pragma unroll
    for (int mi = 0; mi < 2; ++mi) {
        #pragma unroll
        for (int ni = 0; ni < 4; ++ni) {
            int prow = wm*32 + mi*16 + lg*4;
            int co   = wn*64 + ni*16 + lr;
            #pragma unroll
            for (int r = 0; r < 4; ++r)
                outraw[(pix0 + prow + r)*128 + co] = acc[mi][ni][r];
        }
    }
}

// d_out <- m1 ? raw*sc2+bi2 : 0 (f32 in-place)
__global__ __launch_bounds__(256) void apply_kernel(float* __restrict__ out,
                                                    const uchar* __restrict__ m1,
                                                    const float* __restrict__ sb)
{
    int idx4 = blockIdx.x * 256 + threadIdx.x;   // 2,097,152 float4s
    int pos = idx4 >> 5;
    int c4  = (idx4 & 31) << 2;
    float4 v = ((const float4*)out)[idx4];
    float4 r = make_float4(0.f, 0.f, 0.f, 0.f);
    if (m1[pos]) {
        r.x = fmaf(v.x, sb[c4+0], sb[128+c4+0]);
        r.y = fmaf(v.y, sb[c4+1], sb[128+c4+1]);
        r.z = fmaf(v.z, sb[c4+2], sb[128+c4+2]);
        r.w = fmaf(v.w, sb[c4+3], sb[128+c4+3]);
    }
    ((float4*)out)[idx4] = r;
}

extern "C" void kernel_launch(void* const* d_in, const int* in_sizes, int n_in,
                              void* d_out, int out_size, void* d_ws, size_t ws_size,
                              hipStream_t stream)
{
    const float* x      = (const float*)d_in[0];
    const int*   mask   = (const int*)d_in[1];
    const float* w1     = (const float*)d_in[2];
    const float* gamma1 = (const float*)d_in[3];
    const float* beta1  = (const float*)d_in[4];
    const float* w2     = (const float*)d_in[5];
    const float* gamma2 = (const float*)d_in[6];
    const float* beta2  = (const float*)d_in[7];

    // workspace (~17.3 MB)
    ushort* out1 = (ushort*)d_ws;                    // 65536*128 bf16
    ushort* w1T  = out1 + 8388608;                   // 9*128*64
    ushort* w2T  = w1T + 73728;                      // 9*128*128
    float* stats = (float*)(w2T + 147456);           // 512 (256 per BN)
    float* sb    = stats + 512;                      // 512 (256 per BN)
    int*   cnt   = (int*)(sb + 512);                 // 4
    uchar* m1    = (uchar*)(cnt + 4);                // 65536

    // xb (masked bf16 input, 33.55 MB) lives in d_out; consumed by conv1
    // before conv2 overwrites d_out with raw f32 output.
    ushort* xb = (ushort*)d_out;
    float*  out = (float*)d_out;

    hipMemsetAsync(stats, 0, (512 + 512 + 4) * sizeof(float), stream);

    mask_kernel <<<256,  256, 0, stream>>>(mask, m1, cnt);
    xcvt_kernel <<<8192, 256, 0, stream>>>(x, mask, xb);
    wcvt_kernel <<<864,  256, 0, stream>>>(w1, w2, w1T, w2T);
    conv1_mfma  <<<1024, 256, 0, stream>>>(xb, w1T, out1);
    stats_kernel<<<256,  256, 0, stream>>>(out1, 1, m1, stats);
    finalize_kernel<<<1, 128, 0, stream>>>(stats, gamma1, beta1, sb, cnt);
    conv2_mfma  <<<1024, 256, 0, stream>>>(out1, w2T, m1, sb, out);
    stats_kernel<<<256,  256, 0, stream>>>(out, 0, m1, stats + 256);
    finalize_kernel<<<1, 128, 0, stream>>>(stats + 256, gamma2, beta2, sb + 256, cnt);
    apply_kernel<<<8192, 256, 0, stream>>>(out, m1, sb + 256);
}

// Round 7
// 182.592 us; speedup vs baseline: 4.6955x; 1.5047x over previous
//
#include <hip/hip_runtime.h>

#define EPS_BN 1e-5f
#define MFMA16 __builtin_amdgcn_mfma_f32_16x16x32_bf16

typedef unsigned char uchar;
typedef short short8 __attribute__((ext_vector_type(8)));
typedef float f32x4 __attribute__((ext_vector_type(4)));

__device__ __forceinline__ ushort f2bf(float f) {
    unsigned u = __float_as_uint(f);
    return (ushort)((u + 0x7FFFu + ((u >> 16) & 1u)) >> 16);   // RNE
}
__device__ __forceinline__ float bf2f(ushort h) {
    return __uint_as_float(((unsigned)h) << 16);
}
// async global->LDS, 16B per lane; lds dest = wave-uniform base + lane*16
__device__ __forceinline__ void gload_lds16(const void* g, void* l) {
    __builtin_amdgcn_global_load_lds(
        (const __attribute__((address_space(1))) void*)g,
        (__attribute__((address_space(3))) void*)l, 16, 0, 0);
}

// ---------------------------------------------------------------------------
// x[4,256,256,64] f32, mask[4,256,256] i32 (active==0), w1[3,3,64,128],
// w2[3,3,128,128], out[4,128,128,128] f32.
// Convs as implicit GEMM, m97-style: tile M=128px x N=128co, BK=64,
// A+B staged via global_load_lds (dbuf, 2 barriers/step).
// LDS chunk swizzle: LDS[row][cd] holds G[row][cd ^ (row&7)] (16B chunks);
// frag read addr = (row*128 + ks*64 + lg*16) ^ ((row&7)<<4).
// MFMA fragment maps (mfma_f32_16x16x32_bf16):
//   A: lane(lr,lg)=lr+16*lg holds A[row=lr][k=lg*8..+8)
//   B: lane holds B[k=lg*8..+8)[col=lr]; weights stored [co][ci] so co=col
//   D: lane holds D[row=lg*4+r][col=lr], r=0..3
// ---------------------------------------------------------------------------

__global__ __launch_bounds__(256) void mask_kernel(const int* __restrict__ mask,
                                                   uchar* __restrict__ m1,
                                                   int* __restrict__ cnt)
{
    int idx = blockIdx.x * 256 + threadIdx.x;   // 65536
    int ow = idx & 127;
    int oh = (idx >> 7) & 127;
    int b  = idx >> 14;
    bool act = false;
    #pragma unroll
    for (int kh = 0; kh < 3; ++kh) {
        int ih = 2*oh - 1 + kh;
        if ((unsigned)ih >= 256u) continue;
        #pragma unroll
        for (int kw = 0; kw < 3; ++kw) {
            int iw = 2*ow - 1 + kw;
            if ((unsigned)iw >= 256u) continue;
            if (mask[(b*256 + ih)*256 + iw] == 0) act = true;
        }
    }
    m1[idx] = act ? 1 : 0;
    unsigned long long bal = __ballot(act);
    if ((threadIdx.x & 63) == 0)
        atomicAdd(cnt, (int)__popcll(bal));
}

// masked input -> bf16: xb[px*64 + ci]
__global__ __launch_bounds__(256) void xcvt_kernel(const float* __restrict__ x,
                                                   const int* __restrict__ mask,
                                                   ushort* __restrict__ xb)
{
    int idx = blockIdx.x * 256 + threadIdx.x;   // 2,097,152 chunks of 8
    int px = idx >> 3;
    int c0 = (idx & 7) * 8;
    short8 o = {0,0,0,0,0,0,0,0};
    if (mask[px] == 0) {
        const float* p = x + (size_t)px * 64 + c0;
        #pragma unroll
        for (int j = 0; j < 8; ++j) o[j] = (short)f2bf(p[j]);
    }
    *(short8*)(xb + (size_t)px * 64 + c0) = o;
}

// weights -> bf16, transposed to [kh*3+kw][co][ci]
__global__ __launch_bounds__(256) void wcvt_kernel(const float* __restrict__ w1,
                                                   const float* __restrict__ w2,
                                                   ushort* __restrict__ w1T,
                                                   ushort* __restrict__ w2T)
{
    int idx = blockIdx.x * 256 + threadIdx.x;   // 221184 total
    if (idx < 73728) {                          // 9*128*64
        int ci = idx & 63;
        int co = (idx >> 6) & 127;
        int s  = idx >> 13;
        w1T[idx] = f2bf(w1[(s*64 + ci)*128 + co]);
    } else if (idx < 221184) {
        int i  = idx - 73728;                   // 9*128*128
        int ci = i & 127;
        int co = (i >> 7) & 127;
        int s  = i >> 14;
        w2T[i] = f2bf(w2[(s*128 + ci)*128 + co]);
    }
}

// conv1: 3x3 s2, 64->128. Block = output row (b,oh): 128 px x 128 co.
// K = 9 steps x BK=64 (full Cin).
__global__ __launch_bounds__(256) void conv1_mfma(const ushort* __restrict__ xb,
                                                  const ushort* __restrict__ w1T,
                                                  const ushort* __restrict__ zp,
                                                  ushort* __restrict__ out1)
{
    __shared__ ushort At[2][8192];   // 16KB each: [128px][64ci] chunk-swizzled
    __shared__ ushort Bt[2][8192];   // [128co][64ci]

    const int t     = threadIdx.x;
    const int lane  = t & 63;
    const int wv    = t >> 6;
    const int wbase = t & ~63;
    const int blk   = blockIdx.x;    // 512 = b*128 + oh
    const int oh    = blk & 127;
    const int b     = blk >> 7;

    const int wm = wv >> 1, wn = wv & 1;
    const int lr = lane & 15, lg = lane >> 4;

    auto dma = [&](int bf, int s) {
        const int kh = s / 3, kw = s % 3;
        const int ih = 2*oh + kh - 1;
        const bool rowok = ((unsigned)ih < 256u);
        const ushort* arow = xb + (size_t)(b*256 + ih) * 256 * 64;
        #pragma unroll
        for (int r = 0; r < 4; ++r) {
            int idx = r*256 + t;
            int px = idx >> 3, cd = idx & 7, cs = cd ^ (px & 7);
            int iw = 2*px + kw - 1;
            const ushort* g = (rowok && (unsigned)iw < 256u)
                              ? arow + (size_t)iw*64 + cs*8 : zp;
            gload_lds16(g, &At[bf][(size_t)(r*256 + wbase)*8]);
        }
        const ushort* brow = w1T + (size_t)s * 8192;
        #pragma unroll
        for (int r = 0; r < 4; ++r) {
            int idx = r*256 + t;
            int co = idx >> 3, cd = idx & 7, cs = cd ^ (co & 7);
            gload_lds16(brow + (size_t)co*64 + cs*8,
                        &Bt[bf][(size_t)(r*256 + wbase)*8]);
        }
    };

    f32x4 acc[4][4];
    #pragma unroll
    for (int mi = 0; mi < 4; ++mi)
        #pragma unroll
        for (int ni = 0; ni < 4; ++ni)
            acc[mi][ni] = (f32x4){0.f, 0.f, 0.f, 0.f};

    dma(0, 0);
    __syncthreads();
    for (int kt = 0; kt < 9; ++kt) {
        const int cb = kt & 1;
        if (kt < 8) dma(cb ^ 1, kt + 1);
        const char* Ab = (const char*)At[cb];
        const char* Bb = (const char*)Bt[cb];
        #pragma unroll
        for (int ks = 0; ks < 2; ++ks) {
            short8 af[4], bfr[4];
            #pragma unroll
            for (int mi = 0; mi < 4; ++mi) {
                int px = wm*64 + mi*16 + lr;
                af[mi] = *(const short8*)(Ab + ((px*128 + ks*64 + lg*16) ^ ((px & 7) << 4)));
            }
            #pragma unroll
            for (int ni = 0; ni < 4; ++ni) {
                int co = wn*64 + ni*16 + lr;
                bfr[ni] = *(const short8*)(Bb + ((co*128 + ks*64 + lg*16) ^ ((co & 7) << 4)));
            }
            #pragma unroll
            for (int mi = 0; mi < 4; ++mi)
                #pragma unroll
                for (int ni = 0; ni < 4; ++ni)
                    acc[mi][ni] = MFMA16(af[mi], bfr[ni], acc[mi][ni], 0, 0, 0);
        }
        __syncthreads();
    }

    const size_t pixbase = (size_t)blk * 128;
    #pragma unroll
    for (int mi = 0; mi < 4; ++mi) {
        #pragma unroll
        for (int ni = 0; ni < 4; ++ni) {
            int px = wm*64 + mi*16 + lg*4;
            int co = wn*64 + ni*16 + lr;
            #pragma unroll
            for (int r = 0; r < 4; ++r)
                out1[(pixbase + px + r)*128 + co] = f2bf(acc[mi][ni][r]);
        }
    }
}

// conv2: 3x3 s1, 128->128 on bnrelu'd out1. K = 9 steps x 2 halves x BK=64.
__global__ __launch_bounds__(256) void conv2_mfma(const ushort* __restrict__ a,
                                                  const ushort* __restrict__ w2T,
                                                  const ushort* __restrict__ zp,
                                                  float* __restrict__ outraw)
{
    __shared__ ushort At[2][8192];
    __shared__ ushort Bt[2][8192];

    const int t     = threadIdx.x;
    const int lane  = t & 63;
    const int wv    = t >> 6;
    const int wbase = t & ~63;
    const int blk   = blockIdx.x;    // 512 = b*128 + oh
    const int oh    = blk & 127;
    const int b     = blk >> 7;

    const int wm = wv >> 1, wn = wv & 1;
    const int lr = lane & 15, lg = lane >> 4;

    auto dma = [&](int bf, int kt) {
        const int s = kt >> 1, h = kt & 1;
        const int kh = s / 3, kw = s % 3;
        const int ih = oh + kh - 1;
        const bool rowok = ((unsigned)ih < 128u);
        const ushort* arow = a + (size_t)(b*128 + ih) * 128 * 128;
        #pragma unroll
        for (int r = 0; r < 4; ++r) {
            int idx = r*256 + t;
            int px = idx >> 3, cd = idx & 7, cs = cd ^ (px & 7);
            int iw = px + kw - 1;
            const ushort* g = (rowok && (unsigned)iw < 128u)
                              ? arow + (size_t)iw*128 + h*64 + cs*8 : zp;
            gload_lds16(g, &At[bf][(size_t)(r*256 + wbase)*8]);
        }
        const ushort* brow = w2T + (size_t)s * 16384 + h*64;
        #pragma unroll
        for (int r = 0; r < 4; ++r) {
            int idx = r*256 + t;
            int co = idx >> 3, cd = idx & 7, cs = cd ^ (co & 7);
            gload_lds16(brow + (size_t)co*128 + cs*8,
                        &Bt[bf][(size_t)(r*256 + wbase)*8]);
        }
    };

    f32x4 acc[4][4];
    #pragma unroll
    for (int mi = 0; mi < 4; ++mi)
        #pragma unroll
        for (int ni = 0; ni < 4; ++ni)
            acc[mi][ni] = (f32x4){0.f, 0.f, 0.f, 0.f};

    dma(0, 0);
    __syncthreads();
    for (int kt = 0; kt < 18; ++kt) {
        const int cb = kt & 1;
        if (kt < 17) dma(cb ^ 1, kt + 1);
        const char* Ab = (const char*)At[cb];
        const char* Bb = (const char*)Bt[cb];
        #pragma unroll
        for (int ks = 0; ks < 2; ++ks) {
            short8 af[4], bfr[4];
            #pragma unroll
            for (int mi = 0; mi < 4; ++mi) {
                int px = wm*64 + mi*16 + lr;
                af[mi] = *(const short8*)(Ab + ((px*128 + ks*64 + lg*16) ^ ((px & 7) << 4)));
            }
            #pragma unroll
            for (int ni = 0; ni < 4; ++ni) {
                int co = wn*64 + ni*16 + lr;
                bfr[ni] = *(const short8*)(Bb + ((co*128 + ks*64 + lg*16) ^ ((co & 7) << 4)));
            }
            #pragma unroll
            for (int mi = 0; mi < 4; ++mi)
                #pragma unroll
                for (int ni = 0; ni < 4; ++ni)
                    acc[mi][ni] = MFMA16(af[mi], bfr[ni], acc[mi][ni], 0, 0, 0);
        }
        __syncthreads();
    }

    const size_t pixbase = (size_t)blk * 128;
    #pragma unroll
    for (int mi = 0; mi < 4; ++mi) {
        #pragma unroll
        for (int ni = 0; ni < 4; ++ni) {
            int px = wm*64 + mi*16 + lg*4;
            int co = wn*64 + ni*16 + lr;
            #pragma unroll
            for (int r = 0; r < 4; ++r)
                outraw[(pixbase + px + r)*128 + co] = acc[mi][ni][r];
        }
    }
}

// stats over active pixels: stats[0..127]=sum, [128..255]=sumsq
__global__ __launch_bounds__(256) void stats_kernel(const void* __restrict__ src,
                                                    int isbf16,
                                                    const uchar* __restrict__ m1,
                                                    float* __restrict__ stats)
{
    const int t = threadIdx.x;
    const int c = t & 127;
    const int half = t >> 7;
    const int p0 = blockIdx.x * 256 + half * 128;   // 256 blocks x 256 pixels
    float s = 0.f, q = 0.f;
    for (int i = 0; i < 128; ++i) {
        int p = p0 + i;
        if (!m1[p]) continue;
        float v = isbf16 ? bf2f(((const ushort*)src)[(size_t)p*128 + c])
                         : ((const float*)src)[(size_t)p*128 + c];
        s += v;
        q += v * v;
    }
    __shared__ float red[256];
    red[t] = s;
    __syncthreads();
    if (half == 0) atomicAdd(&stats[c], red[c] + red[128 + c]);
    __syncthreads();
    red[t] = q;
    __syncthreads();
    if (half == 0) atomicAdd(&stats[128 + c], red[c] + red[128 + c]);
}

__global__ void finalize_kernel(const float* __restrict__ stats,
                                const float* __restrict__ gamma,
                                const float* __restrict__ beta,
                                float* __restrict__ sbout,
                                const int* __restrict__ cnt)
{
    int c = threadIdx.x;   // 128
    float n = (float)(*cnt);
    float mean = stats[c] / n;
    float var  = stats[128 + c] / n - mean*mean;
    var = fmaxf(var, 0.f);
    float scale = gamma[c] * rsqrtf(var + EPS_BN);
    sbout[c]       = scale;
    sbout[128 + c] = beta[c] - mean*scale;
}

// out1 <- m1 ? relu(out1*sc+bi) : 0   (bf16 in-place)
__global__ __launch_bounds__(256) void bnrelu_kernel(ushort* __restrict__ o,
                                                     const uchar* __restrict__ m1,
                                                     const float* __restrict__ sb)
{
    int idx = blockIdx.x * 256 + threadIdx.x;   // 1,048,576 chunks of 8
    int px = idx >> 4;
    int c0 = (idx & 15) * 8;
    short8 r = {0,0,0,0,0,0,0,0};
    if (m1[px]) {
        short8 v = *(const short8*)(o + (size_t)px*128 + c0);
        #pragma unroll
        for (int j = 0; j < 8; ++j) {
            float f = fmaf(bf2f((ushort)v[j]), sb[c0+j], sb[128+c0+j]);
            r[j] = (short)f2bf(fmaxf(f, 0.f));
        }
    }
    *(short8*)(o + (size_t)px*128 + c0) = r;
}

// d_out <- m1 ? raw*sc2+bi2 : 0 (f32 in-place)
__global__ __launch_bounds__(256) void apply_kernel(float* __restrict__ out,
                                                    const uchar* __restrict__ m1,
                                                    const float* __restrict__ sb)
{
    int idx4 = blockIdx.x * 256 + threadIdx.x;   // 2,097,152 float4s
    int pos = idx4 >> 5;
    int c4  = (idx4 & 31) << 2;
    float4 v = ((const float4*)out)[idx4];
    float4 r = make_float4(0.f, 0.f, 0.f, 0.f);
    if (m1[pos]) {
        r.x = fmaf(v.x, sb[c4+0], sb[128+c4+0]);
        r.y = fmaf(v.y, sb[c4+1], sb[128+c4+1]);
        r.z = fmaf(v.z, sb[c4+2], sb[128+c4+2]);
        r.w = fmaf(v.w, sb[c4+3], sb[128+c4+3]);
    }
    ((float4*)out)[idx4] = r;
}

extern "C" void kernel_launch(void* const* d_in, const int* in_sizes, int n_in,
                              void* d_out, int out_size, void* d_ws, size_t ws_size,
                              hipStream_t stream)
{
    const float* x      = (const float*)d_in[0];
    const int*   mask   = (const int*)d_in[1];
    const float* w1     = (const float*)d_in[2];
    const float* gamma1 = (const float*)d_in[3];
    const float* beta1  = (const float*)d_in[4];
    const float* w2     = (const float*)d_in[5];
    const float* gamma2 = (const float*)d_in[6];
    const float* beta2  = (const float*)d_in[7];

    // workspace (~17.3 MB)
    ushort* out1 = (ushort*)d_ws;                    // 65536*128 bf16
    ushort* w1T  = out1 + 8388608;                   // 9*128*64
    ushort* w2T  = w1T + 73728;                      // 9*128*128
    float* stats = (float*)(w2T + 147456);           // 512 (256 per BN)
    float* sb    = stats + 512;                      // 512 (256 per BN)
    int*   cnt   = (int*)(sb + 512);                 // 4
    ushort* zp   = (ushort*)(cnt + 4);               // 128 (zero page, 256B)
    uchar* m1    = (uchar*)(zp + 128);               // 65536

    // xb (masked bf16 input, 33.55 MB) lives in d_out; consumed by conv1
    // before conv2 overwrites d_out with raw f32 output.
    ushort* xb = (ushort*)d_out;
    float*  out = (float*)d_out;

    // zero stats + sb + cnt + zp (4368 bytes, contiguous)
    hipMemsetAsync(stats, 0, 1024*sizeof(float) + 4*sizeof(int) + 256, stream);

    mask_kernel <<<256,  256, 0, stream>>>(mask, m1, cnt);
    xcvt_kernel <<<8192, 256, 0, stream>>>(x, mask, xb);
    wcvt_kernel <<<864,  256, 0, stream>>>(w1, w2, w1T, w2T);
    conv1_mfma  <<<512,  256, 0, stream>>>(xb, w1T, zp, out1);
    stats_kernel<<<256,  256, 0, stream>>>(out1, 1, m1, stats);
    finalize_kernel<<<1, 128, 0, stream>>>(stats, gamma1, beta1, sb, cnt);
    bnrelu_kernel<<<4096,256, 0, stream>>>(out1, m1, sb);
    conv2_mfma  <<<512,  256, 0, stream>>>(out1, w2T, zp, out);
    stats_kernel<<<256,  256, 0, stream>>>(out, 0, m1, stats + 256);
    finalize_kernel<<<1, 128, 0, stream>>>(stats + 256, gamma2, beta2, sb + 256, cnt);
    apply_kernel<<<8192, 256, 0, stream>>>(out, m1, sb + 256);
}

// Round 8
// 123.255 us; speedup vs baseline: 6.9560x; 1.4814x over previous
//
#include <hip/hip_runtime.h>

#define EPS_BN 1e-5f
#define MFMA16 __builtin_amdgcn_mfma_f32_16x16x32_bf16

typedef unsigned char uchar;
typedef short short8 __attribute__((ext_vector_type(8)));
typedef float f32x4 __attribute__((ext_vector_type(4)));

__device__ __forceinline__ ushort f2bf(float f) {
    unsigned u = __float_as_uint(f);
    return (ushort)((u + 0x7FFFu + ((u >> 16) & 1u)) >> 16);   // RNE
}
__device__ __forceinline__ float bf2f(ushort h) {
    return __uint_as_float(((unsigned)h) << 16);
}
// async global->LDS, 16B per lane; lds dest = wave-uniform base + lane*16
__device__ __forceinline__ void gload_lds16(const void* g, void* l) {
    __builtin_amdgcn_global_load_lds(
        (const __attribute__((address_space(1))) void*)g,
        (__attribute__((address_space(3))) void*)l, 16, 0, 0);
}

// ---------------------------------------------------------------------------
// x[4,256,256,64] f32, mask[4,256,256] i32 (active==0), w1[3,3,64,128],
// w2[3,3,128,128], out[4,128,128,128] f32.
// Convs as implicit GEMM (m97-style gload_lds dbuf). BN stats fused into
// conv epilogues (per-block LDS reduce + f32 atomics), so no stats passes.
// LDS chunk swizzle: LDS[row][cd] holds G[row][cd ^ (row&7)] (16B chunks);
// frag read addr = (row*128 + ks*64 + lg*16) ^ ((row&7)<<4).
// MFMA fragment maps (mfma_f32_16x16x32_bf16):
//   A: lane(lr,lg)=lr+16*lg holds A[row=lr][k=lg*8..+8)
//   B: lane holds B[k=lg*8..+8)[col=lr]; weights stored [co][ci] so co=col
//   D: lane holds D[row=lg*4+r][col=lr], r=0..3
// ---------------------------------------------------------------------------

__global__ __launch_bounds__(256) void mask_kernel(const int* __restrict__ mask,
                                                   uchar* __restrict__ m1,
                                                   int* __restrict__ cnt)
{
    int idx = blockIdx.x * 256 + threadIdx.x;   // 65536
    int ow = idx & 127;
    int oh = (idx >> 7) & 127;
    int b  = idx >> 14;
    bool act = false;
    #pragma unroll
    for (int kh = 0; kh < 3; ++kh) {
        int ih = 2*oh - 1 + kh;
        if ((unsigned)ih >= 256u) continue;
        #pragma unroll
        for (int kw = 0; kw < 3; ++kw) {
            int iw = 2*ow - 1 + kw;
            if ((unsigned)iw >= 256u) continue;
            if (mask[(b*256 + ih)*256 + iw] == 0) act = true;
        }
    }
    m1[idx] = act ? 1 : 0;
    unsigned long long bal = __ballot(act);
    if ((threadIdx.x & 63) == 0)
        atomicAdd(cnt, (int)__popcll(bal));
}

// masked input -> bf16: xb[px*64 + ci]
__global__ __launch_bounds__(256) void xcvt_kernel(const float* __restrict__ x,
                                                   const int* __restrict__ mask,
                                                   ushort* __restrict__ xb)
{
    int idx = blockIdx.x * 256 + threadIdx.x;   // 2,097,152 chunks of 8
    int px = idx >> 3;
    int c0 = (idx & 7) * 8;
    short8 o = {0,0,0,0,0,0,0,0};
    if (mask[px] == 0) {
        const float* p = x + (size_t)px * 64 + c0;
        #pragma unroll
        for (int j = 0; j < 8; ++j) o[j] = (short)f2bf(p[j]);
    }
    *(short8*)(xb + (size_t)px * 64 + c0) = o;
}

// weights -> bf16, transposed to [kh*3+kw][co][ci]
__global__ __launch_bounds__(256) void wcvt_kernel(const float* __restrict__ w1,
                                                   const float* __restrict__ w2,
                                                   ushort* __restrict__ w1T,
                                                   ushort* __restrict__ w2T)
{
    int idx = blockIdx.x * 256 + threadIdx.x;   // 221184 total
    if (idx < 73728) {                          // 9*128*64
        int ci = idx & 63;
        int co = (idx >> 6) & 127;
        int s  = idx >> 13;
        w1T[idx] = f2bf(w1[(s*64 + ci)*128 + co]);
    } else if (idx < 221184) {
        int i  = idx - 73728;                   // 9*128*128
        int ci = i & 127;
        int co = (i >> 7) & 127;
        int s  = i >> 14;
        w2T[i] = f2bf(w2[(s*128 + ci)*128 + co]);
    }
}

// conv1: 3x3 s2, 64->128. Block = output row (b,oh): 128 px x 128 co.
// K = 9 steps x BK=64 (full Cin). Stats epilogue -> stats[0..255].
__global__ __launch_bounds__(256) void conv1_mfma(const ushort* __restrict__ xb,
                                                  const ushort* __restrict__ w1T,
                                                  const ushort* __restrict__ zp,
                                                  const uchar* __restrict__ m1,
                                                  ushort* __restrict__ out1,
                                                  float* __restrict__ stats)
{
    __shared__ ushort At[2][8192];   // 16KB each: [128px][64ci] chunk-swizzled
    __shared__ ushort Bt[2][8192];   // [128co][64ci]

    const int t     = threadIdx.x;
    const int lane  = t & 63;
    const int wv    = t >> 6;
    const int wbase = t & ~63;
    const int blk   = blockIdx.x;    // 512 = b*128 + oh
    const int oh    = blk & 127;
    const int b     = blk >> 7;

    const int wm = wv >> 1, wn = wv & 1;
    const int lr = lane & 15, lg = lane >> 4;

    auto dma = [&](int bf, int s) {
        const int kh = s / 3, kw = s % 3;
        const int ih = 2*oh + kh - 1;
        const bool rowok = ((unsigned)ih < 256u);
        const ushort* arow = xb + (size_t)(b*256 + ih) * 256 * 64;
        #pragma unroll
        for (int r = 0; r < 4; ++r) {
            int idx = r*256 + t;
            int px = idx >> 3, cd = idx & 7, cs = cd ^ (px & 7);
            int iw = 2*px + kw - 1;
            const ushort* g = (rowok && (unsigned)iw < 256u)
                              ? arow + (size_t)iw*64 + cs*8 : zp;
            gload_lds16(g, &At[bf][(size_t)(r*256 + wbase)*8]);
        }
        const ushort* brow = w1T + (size_t)s * 8192;
        #pragma unroll
        for (int r = 0; r < 4; ++r) {
            int idx = r*256 + t;
            int co = idx >> 3, cd = idx & 7, cs = cd ^ (co & 7);
            gload_lds16(brow + (size_t)co*64 + cs*8,
                        &Bt[bf][(size_t)(r*256 + wbase)*8]);
        }
    };

    f32x4 acc[4][4];
    #pragma unroll
    for (int mi = 0; mi < 4; ++mi)
        #pragma unroll
        for (int ni = 0; ni < 4; ++ni)
            acc[mi][ni] = (f32x4){0.f, 0.f, 0.f, 0.f};

    dma(0, 0);
    __syncthreads();
    for (int kt = 0; kt < 9; ++kt) {
        const int cb = kt & 1;
        if (kt < 8) dma(cb ^ 1, kt + 1);
        const char* Ab = (const char*)At[cb];
        const char* Bb = (const char*)Bt[cb];
        #pragma unroll
        for (int ks = 0; ks < 2; ++ks) {
            short8 af[4], bfr[4];
            #pragma unroll
            for (int mi = 0; mi < 4; ++mi) {
                int px = wm*64 + mi*16 + lr;
                af[mi] = *(const short8*)(Ab + ((px*128 + ks*64 + lg*16) ^ ((px & 7) << 4)));
            }
            #pragma unroll
            for (int ni = 0; ni < 4; ++ni) {
                int co = wn*64 + ni*16 + lr;
                bfr[ni] = *(const short8*)(Bb + ((co*128 + ks*64 + lg*16) ^ ((co & 7) << 4)));
            }
            #pragma unroll
            for (int mi = 0; mi < 4; ++mi)
                #pragma unroll
                for (int ni = 0; ni < 4; ++ni)
                    acc[mi][ni] = MFMA16(af[mi], bfr[ni], acc[mi][ni], 0, 0, 0);
        }
        __syncthreads();
    }

    const size_t pixbase = (size_t)blk * 128;
    #pragma unroll
    for (int mi = 0; mi < 4; ++mi) {
        #pragma unroll
        for (int ni = 0; ni < 4; ++ni) {
            int px = wm*64 + mi*16 + lg*4;
            int co = wn*64 + ni*16 + lr;
            #pragma unroll
            for (int r = 0; r < 4; ++r)
                out1[(pixbase + px + r)*128 + co] = f2bf(acc[mi][ni][r]);
        }
    }

    // ---- fused BN1 stats: per-channel masked sum / sumsq over 128 px ----
    float s4[4] = {0.f,0.f,0.f,0.f}, q4[4] = {0.f,0.f,0.f,0.f};
    #pragma unroll
    for (int mi = 0; mi < 4; ++mi) {
        const uchar* mp = m1 + pixbase + wm*64 + mi*16 + lg*4;
        #pragma unroll
        for (int r = 0; r < 4; ++r) {
            float a = mp[r] ? 1.f : 0.f;
            #pragma unroll
            for (int ni = 0; ni < 4; ++ni) {
                float av = a * acc[mi][ni][r];
                s4[ni] += av;
                q4[ni] += av * acc[mi][ni][r];
            }
        }
    }
    float* red = (float*)At;          // reuse LDS (K-loop done): 8 x 128
    const int rrow = wm*4 + lg;
    #pragma unroll
    for (int ni = 0; ni < 4; ++ni) red[rrow*128 + wn*64 + ni*16 + lr] = s4[ni];
    __syncthreads();
    if (t < 128) {
        float v = 0.f;
        #pragma unroll
        for (int rr = 0; rr < 8; ++rr) v += red[rr*128 + t];
        atomicAdd(&stats[t], v);
    }
    __syncthreads();
    #pragma unroll
    for (int ni = 0; ni < 4; ++ni) red[rrow*128 + wn*64 + ni*16 + lr] = q4[ni];
    __syncthreads();
    if (t < 128) {
        float v = 0.f;
        #pragma unroll
        for (int rr = 0; rr < 8; ++rr) v += red[rr*128 + t];
        atomicAdd(&stats[128 + t], v);
    }
}

// conv2: 3x3 s1, 128->128 on bnrelu'd out1. K = 18 steps x BK=64.
// Stats epilogue -> stats[0..255] (second bank).
__global__ __launch_bounds__(256) void conv2_mfma(const ushort* __restrict__ a,
                                                  const ushort* __restrict__ w2T,
                                                  const ushort* __restrict__ zp,
                                                  const uchar* __restrict__ m1,
                                                  float* __restrict__ outraw,
                                                  float* __restrict__ stats)
{
    __shared__ ushort At[2][8192];
    __shared__ ushort Bt[2][8192];

    const int t     = threadIdx.x;
    const int lane  = t & 63;
    const int wv    = t >> 6;
    const int wbase = t & ~63;
    const int blk   = blockIdx.x;    // 512 = b*128 + oh
    const int oh    = blk & 127;
    const int b     = blk >> 7;

    const int wm = wv >> 1, wn = wv & 1;
    const int lr = lane & 15, lg = lane >> 4;

    auto dma = [&](int bf, int kt) {
        const int s = kt >> 1, h = kt & 1;
        const int kh = s / 3, kw = s % 3;
        const int ih = oh + kh - 1;
        const bool rowok = ((unsigned)ih < 128u);
        const ushort* arow = a + (size_t)(b*128 + ih) * 128 * 128;
        #pragma unroll
        for (int r = 0; r < 4; ++r) {
            int idx = r*256 + t;
            int px = idx >> 3, cd = idx & 7, cs = cd ^ (px & 7);
            int iw = px + kw - 1;
            const ushort* g = (rowok && (unsigned)iw < 128u)
                              ? arow + (size_t)iw*128 + h*64 + cs*8 : zp;
            gload_lds16(g, &At[bf][(size_t)(r*256 + wbase)*8]);
        }
        const ushort* brow = w2T + (size_t)s * 16384 + h*64;
        #pragma unroll
        for (int r = 0; r < 4; ++r) {
            int idx = r*256 + t;
            int co = idx >> 3, cd = idx & 7, cs = cd ^ (co & 7);
            gload_lds16(brow + (size_t)co*128 + cs*8,
                        &Bt[bf][(size_t)(r*256 + wbase)*8]);
        }
    };

    f32x4 acc[4][4];
    #pragma unroll
    for (int mi = 0; mi < 4; ++mi)
        #pragma unroll
        for (int ni = 0; ni < 4; ++ni)
            acc[mi][ni] = (f32x4){0.f, 0.f, 0.f, 0.f};

    dma(0, 0);
    __syncthreads();
    for (int kt = 0; kt < 18; ++kt) {
        const int cb = kt & 1;
        if (kt < 17) dma(cb ^ 1, kt + 1);
        const char* Ab = (const char*)At[cb];
        const char* Bb = (const char*)Bt[cb];
        #pragma unroll
        for (int ks = 0; ks < 2; ++ks) {
            short8 af[4], bfr[4];
            #pragma unroll
            for (int mi = 0; mi < 4; ++mi) {
                int px = wm*64 + mi*16 + lr;
                af[mi] = *(const short8*)(Ab + ((px*128 + ks*64 + lg*16) ^ ((px & 7) << 4)));
            }
            #pragma unroll
            for (int ni = 0; ni < 4; ++ni) {
                int co = wn*64 + ni*16 + lr;
                bfr[ni] = *(const short8*)(Bb + ((co*128 + ks*64 + lg*16) ^ ((co & 7) << 4)));
            }
            #pragma unroll
            for (int mi = 0; mi < 4; ++mi)
                #pragma unroll
                for (int ni = 0; ni < 4; ++ni)
                    acc[mi][ni] = MFMA16(af[mi], bfr[ni], acc[mi][ni], 0, 0, 0);
        }
        __syncthreads();
    }

    const size_t pixbase = (size_t)blk * 128;
    #pragma unroll
    for (int mi = 0; mi < 4; ++mi) {
        #pragma unroll
        for (int ni = 0; ni < 4; ++ni) {
            int px = wm*64 + mi*16 + lg*4;
            int co = wn*64 + ni*16 + lr;
            #pragma unroll
            for (int r = 0; r < 4; ++r)
                outraw[(pixbase + px + r)*128 + co] = acc[mi][ni][r];
        }
    }

    // ---- fused BN2 stats ----
    float s4[4] = {0.f,0.f,0.f,0.f}, q4[4] = {0.f,0.f,0.f,0.f};
    #pragma unroll
    for (int mi = 0; mi < 4; ++mi) {
        const uchar* mp = m1 + pixbase + wm*64 + mi*16 + lg*4;
        #pragma unroll
        for (int r = 0; r < 4; ++r) {
            float a = mp[r] ? 1.f : 0.f;
            #pragma unroll
            for (int ni = 0; ni < 4; ++ni) {
                float av = a * acc[mi][ni][r];
                s4[ni] += av;
                q4[ni] += av * acc[mi][ni][r];
            }
        }
    }
    float* red = (float*)At;          // reuse LDS: 8 x 128
    const int rrow = wm*4 + lg;
    #pragma unroll
    for (int ni = 0; ni < 4; ++ni) red[rrow*128 + wn*64 + ni*16 + lr] = s4[ni];
    __syncthreads();
    if (t < 128) {
        float v = 0.f;
        #pragma unroll
        for (int rr = 0; rr < 8; ++rr) v += red[rr*128 + t];
        atomicAdd(&stats[t], v);
    }
    __syncthreads();
    #pragma unroll
    for (int ni = 0; ni < 4; ++ni) red[rrow*128 + wn*64 + ni*16 + lr] = q4[ni];
    __syncthreads();
    if (t < 128) {
        float v = 0.f;
        #pragma unroll
        for (int rr = 0; rr < 8; ++rr) v += red[rr*128 + t];
        atomicAdd(&stats[128 + t], v);
    }
}

__global__ void finalize_kernel(const float* __restrict__ stats,
                                const float* __restrict__ gamma,
                                const float* __restrict__ beta,
                                float* __restrict__ sbout,
                                const int* __restrict__ cnt)
{
    int c = threadIdx.x;   // 128
    float n = (float)(*cnt);
    float mean = stats[c] / n;
    float var  = stats[128 + c] / n - mean*mean;
    var = fmaxf(var, 0.f);
    float scale = gamma[c] * rsqrtf(var + EPS_BN);
    sbout[c]       = scale;
    sbout[128 + c] = beta[c] - mean*scale;
}

// out1 <- m1 ? relu(out1*sc+bi) : 0   (bf16 in-place)
__global__ __launch_bounds__(256) void bnrelu_kernel(ushort* __restrict__ o,
                                                     const uchar* __restrict__ m1,
                                                     const float* __restrict__ sb)
{
    int idx = blockIdx.x * 256 + threadIdx.x;   // 1,048,576 chunks of 8
    int px = idx >> 4;
    int c0 = (idx & 15) * 8;
    short8 r = {0,0,0,0,0,0,0,0};
    if (m1[px]) {
        short8 v = *(const short8*)(o + (size_t)px*128 + c0);
        #pragma unroll
        for (int j = 0; j < 8; ++j) {
            float f = fmaf(bf2f((ushort)v[j]), sb[c0+j], sb[128+c0+j]);
            r[j] = (short)f2bf(fmaxf(f, 0.f));
        }
    }
    *(short8*)(o + (size_t)px*128 + c0) = r;
}

// d_out <- m1 ? raw*sc2+bi2 : 0 (f32 in-place)
__global__ __launch_bounds__(256) void apply_kernel(float* __restrict__ out,
                                                    const uchar* __restrict__ m1,
                                                    const float* __restrict__ sb)
{
    int idx4 = blockIdx.x * 256 + threadIdx.x;   // 2,097,152 float4s
    int pos = idx4 >> 5;
    int c4  = (idx4 & 31) << 2;
    float4 v = ((const float4*)out)[idx4];
    float4 r = make_float4(0.f, 0.f, 0.f, 0.f);
    if (m1[pos]) {
        r.x = fmaf(v.x, sb[c4+0], sb[128+c4+0]);
        r.y = fmaf(v.y, sb[c4+1], sb[128+c4+1]);
        r.z = fmaf(v.z, sb[c4+2], sb[128+c4+2]);
        r.w = fmaf(v.w, sb[c4+3], sb[128+c4+3]);
    }
    ((float4*)out)[idx4] = r;
}

extern "C" void kernel_launch(void* const* d_in, const int* in_sizes, int n_in,
                              void* d_out, int out_size, void* d_ws, size_t ws_size,
                              hipStream_t stream)
{
    const float* x      = (const float*)d_in[0];
    const int*   mask   = (const int*)d_in[1];
    const float* w1     = (const float*)d_in[2];
    const float* gamma1 = (const float*)d_in[3];
    const float* beta1  = (const float*)d_in[4];
    const float* w2     = (const float*)d_in[5];
    const float* gamma2 = (const float*)d_in[6];
    const float* beta2  = (const float*)d_in[7];

    // workspace (~17.3 MB)
    ushort* out1 = (ushort*)d_ws;                    // 65536*128 bf16
    ushort* w1T  = out1 + 8388608;                   // 9*128*64
    ushort* w2T  = w1T + 73728;                      // 9*128*128
    float* stats = (float*)(w2T + 147456);           // 512 (256 per BN)
    float* sb    = stats + 512;                      // 512 (256 per BN)
    int*   cnt   = (int*)(sb + 512);                 // 4
    ushort* zp   = (ushort*)(cnt + 4);               // 128 (zero page, 256B)
    uchar* m1    = (uchar*)(zp + 128);               // 65536

    // xb (masked bf16 input, 33.55 MB) lives in d_out; consumed by conv1
    // before conv2 overwrites d_out with raw f32 output.
    ushort* xb = (ushort*)d_out;
    float*  out = (float*)d_out;

    // zero stats + sb + cnt + zp (contiguous)
    hipMemsetAsync(stats, 0, 1024*sizeof(float) + 4*sizeof(int) + 256, stream);

    mask_kernel <<<256,  256, 0, stream>>>(mask, m1, cnt);
    xcvt_kernel <<<8192, 256, 0, stream>>>(x, mask, xb);
    wcvt_kernel <<<864,  256, 0, stream>>>(w1, w2, w1T, w2T);
    conv1_mfma  <<<512,  256, 0, stream>>>(xb, w1T, zp, m1, out1, stats);
    finalize_kernel<<<1, 128, 0, stream>>>(stats, gamma1, beta1, sb, cnt);
    bnrelu_kernel<<<4096,256, 0, stream>>>(out1, m1, sb);
    conv2_mfma  <<<512,  256, 0, stream>>>(out1, w2T, zp, m1, out, stats + 256);
    finalize_kernel<<<1, 128, 0, stream>>>(stats + 256, gamma2, beta2, sb + 256, cnt);
    apply_kernel<<<8192, 256, 0, stream>>>(out, m1, sb + 256);
}